// Round 5
// baseline (142.821 us; speedup 1.0000x reference)
//
#include <hip/hip_runtime.h>
#include <math.h>

// YOLOv1 loss: S=7, B=2, C=1, BATCH=32768
// predictions: (BATCH, 7, 7, 11) fp32   targets: (BATCH, 7, 7, 6) fp32
// out: 5 fp32 scalars: total, coord/bs, conf_obj/bs, conf_noobj/bs, class/bs
//
// Stage-1: 4 consecutive cells per thread -> pred chunk = exactly 11 aligned
// float4 (176 B), tgt chunk = exactly 6 aligned float4 (96 B). No overlap,
// no misalignment, 17 vmem loads per thread, deep MLP. One float4 partial
// per block -> d_ws. Stage-2: one block reduces partials, writes 5 outputs.

#define PRED_C 11
#define TGT_C  6
#define TPB    256
#define CELLS_PER_THREAD 4
#define CELLS_PER_BLOCK (TPB * CELLS_PER_THREAD)   // 1024
#define LAMBDA_COORD 5.0f
#define LAMBDA_NOOBJ 0.5f
#define EPSV 1e-6f

// fast sigmoid: |rel err| ~1e-6, far inside the 1.98 absmax budget
__device__ __forceinline__ float fsig(float x) {
    return __builtin_amdgcn_rcpf(1.0f + __expf(-x));
}

__device__ __forceinline__ void cell_loss(const float* __restrict__ p,
                                          const float* __restrict__ t,
                                          float& acc_coord, float& acc_cobj,
                                          float& acc_cnoobj, float& acc_cls)
{
    const float tx = t[0], ty = t[1], tw = t[2], th = t[3];
    const float tconf = t[4], tcls = t[5];
    const float obj   = (tconf == 1.0f) ? 1.0f : 0.0f;
    const float noobj = (tconf == 0.0f) ? 1.0f : 0.0f;

    const float t1x = tx - tw * 0.5f, t1y = ty - th * 0.5f;
    const float t2x = tx + tw * 0.5f, t2y = ty + th * 0.5f;
    const float tarea = tw * th;

    float iou[2], sx[2], sy[2], aw[2], ah[2], scf[2];
    #pragma unroll
    for (int bb = 0; bb < 2; ++bb) {
        sx[bb]  = fsig(p[bb * 5 + 0]);
        sy[bb]  = fsig(p[bb * 5 + 1]);
        scf[bb] = fsig(p[bb * 5 + 4]);
        aw[bb]  = fabsf(p[bb * 5 + 2]);
        ah[bb]  = fabsf(p[bb * 5 + 3]);
        const float p1x = sx[bb] - aw[bb] * 0.5f, p1y = sy[bb] - ah[bb] * 0.5f;
        const float p2x = sx[bb] + aw[bb] * 0.5f, p2y = sy[bb] + ah[bb] * 0.5f;
        const float ix = fminf(p2x, t2x) - fmaxf(p1x, t1x);
        const float iy = fminf(p2y, t2y) - fmaxf(p1y, t1y);
        const float inter = fmaxf(ix, 0.0f) * fmaxf(iy, 0.0f);
        const float parea = aw[bb] * ah[bb];
        iou[bb] = inter * __builtin_amdgcn_rcpf(parea + tarea - inter + EPSV);
    }
    // jnp.argmax: first occurrence of max -> box1 only if strictly greater
    const int best = (iou[1] > iou[0]) ? 1 : 0;

    const float dx = sx[best] - tx;
    const float dy = sy[best] - ty;
    const float dw = __builtin_amdgcn_sqrtf(aw[best] + EPSV) -
                     __builtin_amdgcn_sqrtf(tw + EPSV);
    const float dh = __builtin_amdgcn_sqrtf(ah[best] + EPSV) -
                     __builtin_amdgcn_sqrtf(th + EPSV);
    acc_coord += LAMBDA_COORD * obj * ((dx * dx + dy * dy) + (dw * dw + dh * dh));

    const float sc = scf[best];
    acc_cobj += obj * (sc - tconf) * (sc - tconf);

    const float d0 = scf[0] - tconf;
    const float d1 = scf[1] - tconf;
    acc_cnoobj += LAMBDA_NOOBJ * noobj * (d0 * d0 + d1 * d1);

    const float pc = p[10];
    const float bce = fmaxf(pc, 0.0f) - pc * tcls +
                      __logf(1.0f + __expf(-fabsf(pc)));
    acc_cls += obj * bce;
}

__global__ __launch_bounds__(TPB) void yolo_partial_kernel(
    const float* __restrict__ pred,
    const float* __restrict__ tgt,
    float* __restrict__ partials)   // gridDim.x float4s
{
    __shared__ float red[4][4];
    const int tid = threadIdx.x;
    const long long cell0 = (long long)blockIdx.x * CELLS_PER_BLOCK
                          + (long long)tid * CELLS_PER_THREAD;

    // ---- exactly-aligned float4 loads: 11 pred + 6 tgt, all issued up front
    float pr[44];   // 4 cells x 11
    float tg[24];   // 4 cells x 6
    {
        const float4* gp = (const float4*)(pred + cell0 * PRED_C);
        #pragma unroll
        for (int j = 0; j < 11; ++j) ((float4*)pr)[j] = gp[j];
        const float4* gt = (const float4*)(tgt + cell0 * TGT_C);
        #pragma unroll
        for (int j = 0; j < 6; ++j) ((float4*)tg)[j] = gt[j];
    }

    float coord = 0.f, cobj = 0.f, cnoobj = 0.f, cls = 0.f;
    #pragma unroll
    for (int c = 0; c < CELLS_PER_THREAD; ++c)
        cell_loss(pr + c * PRED_C, tg + c * TGT_C, coord, cobj, cnoobj, cls);

    // ---- reduction: wave shuffle (64-wide) -> cross-wave LDS -> float4 store
    #pragma unroll
    for (int off = 32; off >= 1; off >>= 1) {
        coord  += __shfl_down(coord, off);
        cobj   += __shfl_down(cobj, off);
        cnoobj += __shfl_down(cnoobj, off);
        cls    += __shfl_down(cls, off);
    }
    const int wave = tid >> 6;
    const int lane = tid & 63;
    if (lane == 0) {
        red[wave][0] = coord;
        red[wave][1] = cobj;
        red[wave][2] = cnoobj;
        red[wave][3] = cls;
    }
    __syncthreads();
    if (tid == 0) {
        float4 v;
        v.x = red[0][0] + red[1][0] + red[2][0] + red[3][0];
        v.y = red[0][1] + red[1][1] + red[2][1] + red[3][1];
        v.z = red[0][2] + red[1][2] + red[2][2] + red[3][2];
        v.w = red[0][3] + red[1][3] + red[2][3] + red[3][3];
        ((float4*)partials)[blockIdx.x] = v;
    }
}

__global__ __launch_bounds__(1024) void yolo_final_kernel(
    const float* __restrict__ partials,
    float* __restrict__ out,
    int nblk,
    float inv_bs)
{
    __shared__ float red[16][4];
    const int tid = threadIdx.x;

    float c = 0.f, co = 0.f, cn = 0.f, cl = 0.f;
    for (int i = tid; i < nblk; i += 1024) {
        const float4 v = ((const float4*)partials)[i];
        c += v.x; co += v.y; cn += v.z; cl += v.w;
    }
    #pragma unroll
    for (int off = 32; off >= 1; off >>= 1) {
        c  += __shfl_down(c, off);
        co += __shfl_down(co, off);
        cn += __shfl_down(cn, off);
        cl += __shfl_down(cl, off);
    }
    const int wave = tid >> 6;
    const int lane = tid & 63;
    if (lane == 0) {
        red[wave][0] = c;
        red[wave][1] = co;
        red[wave][2] = cn;
        red[wave][3] = cl;
    }
    __syncthreads();
    if (tid == 0) {
        float sc = 0.f, sco = 0.f, scn = 0.f, scl = 0.f;
        #pragma unroll
        for (int w = 0; w < 16; ++w) {
            sc  += red[w][0];
            sco += red[w][1];
            scn += red[w][2];
            scl += red[w][3];
        }
        out[0] = (sc + sco + scn + scl) * inv_bs;
        out[1] = sc  * inv_bs;
        out[2] = sco * inv_bs;
        out[3] = scn * inv_bs;
        out[4] = scl * inv_bs;
    }
}

extern "C" void kernel_launch(void* const* d_in, const int* in_sizes, int n_in,
                              void* d_out, int out_size, void* d_ws, size_t ws_size,
                              hipStream_t stream) {
    const float* pred = (const float*)d_in[0];
    const float* tgt  = (const float*)d_in[1];
    float* out = (float*)d_out;
    float* partials = (float*)d_ws;

    const long long batch = (long long)in_sizes[0] / (7 * 7 * PRED_C);
    const long long cells = batch * 49;                 // 1,605,632
    const int nblk = (int)(cells / CELLS_PER_BLOCK);    // 1568 exact

    yolo_partial_kernel<<<nblk, TPB, 0, stream>>>(pred, tgt, partials);
    yolo_final_kernel<<<1, 1024, 0, stream>>>(partials, out, nblk,
                                              1.0f / (float)batch);
}

// Round 6
// 133.991 us; speedup vs baseline: 1.0659x; 1.0659x over previous
//
#include <hip/hip_runtime.h>
#include <math.h>

// YOLOv1 loss: S=7, B=2, C=1, BATCH=32768
// predictions: (BATCH, 7, 7, 11) fp32   targets: (BATCH, 7, 7, 6) fp32
// out: 5 fp32 scalars: total, coord/bs, conf_obj/bs, conf_noobj/bs, class/bs
//
// Stage-1 (R2 structure + R3 math): perfectly-coalesced float4 staging into
// LDS (1 txn/line, FETCH=53MB), fast-math intrinsics, 6272 independent
// one-tile blocks. One float4 partial per block -> d_ws.
// Stage-2: one 1024-thread block reduces partials, writes all 5 outputs.

#define PRED_C 11
#define TGT_C  6
#define CPB    256            // cells per block == threads per block
#define LAMBDA_COORD 5.0f
#define LAMBDA_NOOBJ 0.5f
#define EPSV 1e-6f

// fast sigmoid: |rel err| ~1e-6, far inside the 1.98 absmax budget
__device__ __forceinline__ float fsig(float x) {
    return __builtin_amdgcn_rcpf(1.0f + __expf(-x));
}

__global__ __launch_bounds__(CPB) void yolo_partial_kernel(
    const float* __restrict__ pred,
    const float* __restrict__ tgt,
    float* __restrict__ partials)   // gridDim.x float4s
{
    __shared__ float sp[CPB * PRED_C];   // 11264 B
    __shared__ float st[CPB * TGT_C];    // 6144 B
    __shared__ float red[4][4];

    const int tid = threadIdx.x;
    const long long blockCell = (long long)blockIdx.x * CPB;

    // ---- stage: fully-coalesced float4 loads into LDS (lane-contiguous) ----
    {
        const float4* gp = (const float4*)(pred + blockCell * PRED_C);
        float4* lp = (float4*)sp;
        lp[tid]       = gp[tid];
        lp[tid + 256] = gp[tid + 256];
        if (tid < CPB * PRED_C / 4 - 512) lp[tid + 512] = gp[tid + 512];
        const float4* gt = (const float4*)(tgt + blockCell * TGT_C);
        float4* lt = (float4*)st;
        lt[tid] = gt[tid];
        if (tid < CPB * TGT_C / 4 - 256) lt[tid + 256] = gt[tid + 256];
    }
    __syncthreads();

    // ---- per-cell loss (stride-11 LDS reads: conflict-free 2-way) ----
    const float* p = sp + tid * PRED_C;
    const float* t = st + tid * TGT_C;

    const float tx = t[0], ty = t[1], tw = t[2], th = t[3];
    const float tconf = t[4], tcls = t[5];
    const float obj   = (tconf == 1.0f) ? 1.0f : 0.0f;
    const float noobj = (tconf == 0.0f) ? 1.0f : 0.0f;

    const float t1x = tx - tw * 0.5f, t1y = ty - th * 0.5f;
    const float t2x = tx + tw * 0.5f, t2y = ty + th * 0.5f;
    const float tarea = tw * th;

    float iou[2], sx[2], sy[2], aw[2], ah[2], scf[2];
    #pragma unroll
    for (int b = 0; b < 2; ++b) {
        sx[b]  = fsig(p[b * 5 + 0]);
        sy[b]  = fsig(p[b * 5 + 1]);
        scf[b] = fsig(p[b * 5 + 4]);
        aw[b]  = fabsf(p[b * 5 + 2]);
        ah[b]  = fabsf(p[b * 5 + 3]);
        const float p1x = sx[b] - aw[b] * 0.5f, p1y = sy[b] - ah[b] * 0.5f;
        const float p2x = sx[b] + aw[b] * 0.5f, p2y = sy[b] + ah[b] * 0.5f;
        const float ix = fminf(p2x, t2x) - fmaxf(p1x, t1x);
        const float iy = fminf(p2y, t2y) - fmaxf(p1y, t1y);
        const float inter = fmaxf(ix, 0.0f) * fmaxf(iy, 0.0f);
        const float parea = aw[b] * ah[b];
        iou[b] = inter * __builtin_amdgcn_rcpf(parea + tarea - inter + EPSV);
    }
    // jnp.argmax: first occurrence of max -> box1 only if strictly greater
    const int best = (iou[1] > iou[0]) ? 1 : 0;

    const float dx = sx[best] - tx;
    const float dy = sy[best] - ty;
    const float dw = __builtin_amdgcn_sqrtf(aw[best] + EPSV) -
                     __builtin_amdgcn_sqrtf(tw + EPSV);
    const float dh = __builtin_amdgcn_sqrtf(ah[best] + EPSV) -
                     __builtin_amdgcn_sqrtf(th + EPSV);
    float coord = LAMBDA_COORD * obj * ((dx * dx + dy * dy) + (dw * dw + dh * dh));

    const float sc = scf[best];
    float conf_obj = obj * (sc - tconf) * (sc - tconf);

    const float d0 = scf[0] - tconf;
    const float d1 = scf[1] - tconf;
    float conf_noobj = LAMBDA_NOOBJ * noobj * (d0 * d0 + d1 * d1);

    const float pc = p[10];
    const float bce = fmaxf(pc, 0.0f) - pc * tcls +
                      __logf(1.0f + __expf(-fabsf(pc)));
    float class_loss = obj * bce;

    // ---- reduction: wave shuffle (64-wide) -> cross-wave LDS -> float4 store
    #pragma unroll
    for (int off = 32; off >= 1; off >>= 1) {
        coord      += __shfl_down(coord, off);
        conf_obj   += __shfl_down(conf_obj, off);
        conf_noobj += __shfl_down(conf_noobj, off);
        class_loss += __shfl_down(class_loss, off);
    }
    const int wave = tid >> 6;
    const int lane = tid & 63;
    if (lane == 0) {
        red[wave][0] = coord;
        red[wave][1] = conf_obj;
        red[wave][2] = conf_noobj;
        red[wave][3] = class_loss;
    }
    __syncthreads();
    if (tid == 0) {
        float4 v;
        v.x = red[0][0] + red[1][0] + red[2][0] + red[3][0];
        v.y = red[0][1] + red[1][1] + red[2][1] + red[3][1];
        v.z = red[0][2] + red[1][2] + red[2][2] + red[3][2];
        v.w = red[0][3] + red[1][3] + red[2][3] + red[3][3];
        ((float4*)partials)[blockIdx.x] = v;
    }
}

__global__ __launch_bounds__(1024) void yolo_final_kernel(
    const float* __restrict__ partials,
    float* __restrict__ out,
    int nblk,
    float inv_bs)
{
    __shared__ float red[16][4];
    const int tid = threadIdx.x;

    float c = 0.f, co = 0.f, cn = 0.f, cl = 0.f;
    for (int i = tid; i < nblk; i += 1024) {
        const float4 v = ((const float4*)partials)[i];
        c += v.x; co += v.y; cn += v.z; cl += v.w;
    }
    #pragma unroll
    for (int off = 32; off >= 1; off >>= 1) {
        c  += __shfl_down(c, off);
        co += __shfl_down(co, off);
        cn += __shfl_down(cn, off);
        cl += __shfl_down(cl, off);
    }
    const int wave = tid >> 6;
    const int lane = tid & 63;
    if (lane == 0) {
        red[wave][0] = c;
        red[wave][1] = co;
        red[wave][2] = cn;
        red[wave][3] = cl;
    }
    __syncthreads();
    if (tid == 0) {
        float sc = 0.f, sco = 0.f, scn = 0.f, scl = 0.f;
        #pragma unroll
        for (int w = 0; w < 16; ++w) {
            sc  += red[w][0];
            sco += red[w][1];
            scn += red[w][2];
            scl += red[w][3];
        }
        out[0] = (sc + sco + scn + scl) * inv_bs;
        out[1] = sc  * inv_bs;
        out[2] = sco * inv_bs;
        out[3] = scn * inv_bs;
        out[4] = scl * inv_bs;
    }
}

extern "C" void kernel_launch(void* const* d_in, const int* in_sizes, int n_in,
                              void* d_out, int out_size, void* d_ws, size_t ws_size,
                              hipStream_t stream) {
    const float* pred = (const float*)d_in[0];
    const float* tgt  = (const float*)d_in[1];
    float* out = (float*)d_out;
    float* partials = (float*)d_ws;

    const long long batch = (long long)in_sizes[0] / (7 * 7 * PRED_C);
    const long long cells = batch * 49;         // 1,605,632
    const int nblk = (int)(cells / CPB);        // 6272 exact

    yolo_partial_kernel<<<nblk, CPB, 0, stream>>>(pred, tgt, partials);
    yolo_final_kernel<<<1, 1024, 0, stream>>>(partials, out, nblk,
                                              1.0f / (float)batch);
}